// Round 15
// baseline (453.953 us; speedup 1.0000x reference)
//
#include <hip/hip_runtime.h>
#include <hip/hip_bf16.h>

// JetGNN: 2-layer SAGEConv(mean) + ReLU + global_mean_pool + Linear(64->2)
// R1: hierarchical scan. R2: bucketed counting-sort CSR build.
// R3: run-flush pool. R4: agg unroll WIN. R5-R8: wave-uniform dense dead end.
// R9: LDS-tiled GEMM WIN. R10: bf16 gather WIN. R11: runtime kIter (VGPR fix).
// R12: MFMA + double-bf16 weights WIN. R13: agg bf16-out WIN (gather byte floor).
// R14: gather+MFMA fusion -- neutral: B-staging LDS (52KB) cut occupancy to
//      28%, gather fell to 1.77 TB/s (vs 3.5 standalone); 1.8M bank conflicts.
// R15: B moves to GLOBAL (prepacked bf16 hi/lo, 32KB, L1/L2-resident): LDS =
//      A_s only (17.4KB) -> 7-8 blocks/CU; gather unroll 8 restored; staging
//      bank conflicts gone. Numerics bit-identical.

#define WS_ALIGN 64
#define EPB 4096          // edges per block in bucket_scatter (256 thr x 16)
#define BSHIFT 10         // 1024 nodes per bucket
#define BNODES 1024

typedef short bf16x8 __attribute__((ext_vector_type(8)));
typedef float f32x4 __attribute__((ext_vector_type(4)));

__device__ inline unsigned short f2bf(float f) {   // RNE f32->bf16 (finite inputs)
    unsigned u = __float_as_uint(f);
    return (unsigned short)((u + 0x7fffu + ((u >> 16) & 1u)) >> 16);
}

__device__ inline float bf2f(unsigned short u) {
    return __uint_as_float((unsigned)u << 16);
}

__device__ inline void acc8(const uint4 u, float* a) {  // 8 bf16 -> fp32 accumulate
    a[0] += __uint_as_float(u.x << 16);
    a[1] += __uint_as_float(u.x & 0xffff0000u);
    a[2] += __uint_as_float(u.y << 16);
    a[3] += __uint_as_float(u.y & 0xffff0000u);
    a[4] += __uint_as_float(u.z << 16);
    a[5] += __uint_as_float(u.z & 0xffff0000u);
    a[6] += __uint_as_float(u.w << 16);
    a[7] += __uint_as_float(u.w & 0xffff0000u);
}

// ---------- pooling counts ----------

__global__ void cnt_kernel(const int* __restrict__ batch, int* __restrict__ cnt, int N) {
    int i = blockIdx.x * blockDim.x + threadIdx.x;
    if (i < N) atomicAdd(&cnt[batch[i]], 1);
}

// ---------- x (f32) -> xb (bf16) ----------

__global__ void cvt_kernel(const float* __restrict__ x, unsigned short* __restrict__ xb,
                           int total4) {
    int i = blockIdx.x * blockDim.x + threadIdx.x;
    if (i >= total4) return;
    const float4 v = reinterpret_cast<const float4*>(x)[i];
    ushort4 o;
    o.x = f2bf(v.x); o.y = f2bf(v.y); o.z = f2bf(v.z); o.w = f2bf(v.w);
    reinterpret_cast<ushort4*>(xb)[i] = o;
}

// ---------- weight prepack: [Wl|Wr] rows -> bf16 hi + lo residual ----------

__global__ void wprep_kernel(const float* __restrict__ Wl, const float* __restrict__ Wr,
                             unsigned short* __restrict__ whi, unsigned short* __restrict__ wlo,
                             int DIN) {
    const int K = 2 * DIN;
    int idx = blockIdx.x * blockDim.x + threadIdx.x;
    if (idx >= 64 * K) return;
    const int o = idx / K, k = idx % K;
    const float v = (k < DIN) ? Wl[o * DIN + k] : Wr[o * DIN + (k - DIN)];
    const unsigned short hi = f2bf(v);
    whi[idx] = hi;
    wlo[idx] = f2bf(v - bf2f(hi));
}

// ---------- bucketed CSR construction ----------

__global__ __launch_bounds__(256) void bucket_hist_kernel(const int* __restrict__ dst,
                                                          int* __restrict__ bucketCount, int E) {
    __shared__ int hist[256];
    const int t = threadIdx.x;
    hist[t] = 0;
    __syncthreads();
    for (int e = blockIdx.x * blockDim.x + t; e < E; e += gridDim.x * blockDim.x)
        atomicAdd(&hist[dst[e] >> BSHIFT], 1);
    __syncthreads();
    if (hist[t] > 0) atomicAdd(&bucketCount[t], hist[t]);
}

__global__ __launch_bounds__(256) void bucket_scan_kernel(const int* __restrict__ bucketCount,
                                                          int* __restrict__ bucketBase,
                                                          int* __restrict__ bucketCursor,
                                                          int NB, int E) {
    __shared__ int s[256];
    const int t = threadIdx.x;
    int v = (t < NB) ? bucketCount[t] : 0;
    s[t] = v;
    __syncthreads();
    for (int off = 1; off < 256; off <<= 1) {
        int u = (t >= off) ? s[t - off] : 0;
        __syncthreads();
        s[t] += u;
        __syncthreads();
    }
    int excl = s[t] - v;
    if (t < NB) { bucketBase[t] = excl; bucketCursor[t] = excl; }
    if (t == 0) bucketBase[NB] = E;
}

__global__ __launch_bounds__(256) void bucket_scatter_kernel(const int* __restrict__ src,
                                                             const int* __restrict__ dst,
                                                             int* __restrict__ bucketCursor,
                                                             unsigned* __restrict__ bucketData,
                                                             int E, int NB) {
    __shared__ int hist[256];
    __shared__ int cur[256];
    const int t = threadIdx.x;
    hist[t] = 0;
    __syncthreads();
    const int eBase = blockIdx.x * EPB + t;
    int s[16], b[16], dl[16];
#pragma unroll
    for (int j = 0; j < 16; ++j) {
        int e = eBase + j * 256;
        if (e < E) {
            int d = dst[e];
            s[j]  = src[e];
            b[j]  = d >> BSHIFT;
            dl[j] = d & (BNODES - 1);
            atomicAdd(&hist[b[j]], 1);
        } else {
            b[j] = -1;
        }
    }
    __syncthreads();
    if (t < NB && hist[t] > 0) cur[t] = atomicAdd(&bucketCursor[t], hist[t]);
    __syncthreads();
#pragma unroll
    for (int j = 0; j < 16; ++j) {
        if (b[j] >= 0) {
            int pos = atomicAdd(&cur[b[j]], 1);
            bucketData[pos] = ((unsigned)s[j] << BSHIFT) | (unsigned)dl[j];
        }
    }
}

__global__ __launch_bounds__(256) void csr_build_kernel(const unsigned* __restrict__ bucketData,
                                                        const int* __restrict__ bucketBase,
                                                        int* __restrict__ offsets,
                                                        int* __restrict__ csr_src,
                                                        int N, int E, int NB) {
    __shared__ int cnt[BNODES];
    __shared__ int sscan[256];
    __shared__ int cur[BNODES];
    const int t   = threadIdx.x;
    const int bkt = blockIdx.x;
    const int beg = bucketBase[bkt];
    const int end = bucketBase[bkt + 1];
    for (int i = t; i < BNODES; i += 256) cnt[i] = 0;
    __syncthreads();
    for (int k = beg + t; k < end; k += 256)
        atomicAdd(&cnt[bucketData[k] & (BNODES - 1)], 1);
    __syncthreads();
    int local[4];
    int sum = 0;
#pragma unroll
    for (int j = 0; j < 4; ++j) { local[j] = sum; sum += cnt[t * 4 + j]; }
    sscan[t] = sum;
    __syncthreads();
    for (int off = 1; off < 256; off <<= 1) {
        int v = (t >= off) ? sscan[t - off] : 0;
        __syncthreads();
        sscan[t] += v;
        __syncthreads();
    }
    int base = (t > 0) ? sscan[t - 1] : 0;
#pragma unroll
    for (int j = 0; j < 4; ++j) cur[t * 4 + j] = base + local[j];
    __syncthreads();
    for (int i = t; i < BNODES; i += 256) {
        int node = (bkt << BSHIFT) + i;
        if (node <= N) offsets[node] = beg + cur[i];
    }
    if (bkt == NB - 1 && t == 0 && (NB << BSHIFT) == N) offsets[N] = E;
    __syncthreads();
    for (int k = beg + t; k < end; k += 256) {
        unsigned v = bucketData[k];
        int d   = (int)(v & (BNODES - 1));
        int pos = beg + atomicAdd(&cur[d], 1);
        csr_src[pos] = (int)(v >> BSHIFT);
    }
}

// ---------- fused gather-mean + MFMA dense (B from global) ----------
// Block = 64 nodes x 64 outs, 4 waves. LDS = A_s only (17.4KB max).
// Phase A: gather-mean (bf16 in, fp32 acc, 8-deep unroll) -> A_s k<DIN;
//          self rows -> k>=DIN.
// MFMA: A frags from LDS; B frags (hi+lo double-bf16) from global prepacked
//       whi/wlo rows [o][k] -- 32KB, L1/L2-resident. nSteps RUNTIME (R11).

template <int DIN, bool POOL>
__launch_bounds__(256)
__global__ void mfma_fused_kernel(const unsigned short* __restrict__ featb,
                                  const int* __restrict__ csr_src,
                                  const int* __restrict__ offsets,
                                  const unsigned short* __restrict__ whi,
                                  const unsigned short* __restrict__ wlo,
                                  const float* __restrict__ bias,
                                  unsigned short* __restrict__ houtb,
                                  const int* __restrict__ batch,
                                  float* __restrict__ pool_sum,
                                  int N, int nSteps) {
    constexpr int K   = 2 * DIN;      // 64 / 128
    constexpr int STR = K + 8;        // 72 / 136 ushorts, rows 16B-aligned
    constexpr int D8  = DIN / 8;      // uint4 chunks per feature row
    __shared__ unsigned short A_s[64 * STR];
    const int tid = threadIdx.x;
    const int nodeBase = blockIdx.x * 64;
    const uint4* fbase = reinterpret_cast<const uint4*>(featb);

    // Phase A1: gather-mean into k [0, DIN). pair = (node, chunk q).
    for (int pairIdx = tid; pairIdx < 64 * D8; pairIdx += 256) {
        const int node = pairIdx / D8;
        const int q    = pairIdx % D8;
        const int n = min(nodeBase + node, N - 1);
        const int beg = offsets[n];
        const int end = offsets[n + 1];
        float a[8] = {0.f, 0.f, 0.f, 0.f, 0.f, 0.f, 0.f, 0.f};
        int k = beg;
        for (; k + 8 <= end; k += 8) {
            int s[8];
#pragma unroll
            for (int j = 0; j < 8; ++j) s[j] = csr_src[k + j];
            uint4 u[8];
#pragma unroll
            for (int j = 0; j < 8; ++j) u[j] = fbase[(size_t)s[j] * D8 + q];
#pragma unroll
            for (int j = 0; j < 8; ++j) acc8(u[j], a);
        }
        for (; k + 4 <= end; k += 4) {
            const int s0 = csr_src[k + 0];
            const int s1 = csr_src[k + 1];
            const int s2 = csr_src[k + 2];
            const int s3 = csr_src[k + 3];
            const uint4 u0 = fbase[(size_t)s0 * D8 + q];
            const uint4 u1 = fbase[(size_t)s1 * D8 + q];
            const uint4 u2 = fbase[(size_t)s2 * D8 + q];
            const uint4 u3 = fbase[(size_t)s3 * D8 + q];
            acc8(u0, a); acc8(u1, a); acc8(u2, a); acc8(u3, a);
        }
        for (; k < end; ++k)
            acc8(fbase[(size_t)csr_src[k] * D8 + q], a);
        const float inv = 1.0f / fmaxf((float)(end - beg), 1.0f);
        ushort4 lo, hi;
        lo.x = f2bf(a[0] * inv); lo.y = f2bf(a[1] * inv);
        lo.z = f2bf(a[2] * inv); lo.w = f2bf(a[3] * inv);
        hi.x = f2bf(a[4] * inv); hi.y = f2bf(a[5] * inv);
        hi.z = f2bf(a[6] * inv); hi.w = f2bf(a[7] * inv);
        unsigned short* dstp = &A_s[node * STR + q * 8];
        *reinterpret_cast<ushort4*>(dstp)     = lo;
        *reinterpret_cast<ushort4*>(dstp + 4) = hi;
    }
    // Phase A2: self rows into k [DIN, 2*DIN)
    for (int i = tid; i < 64 * D8; i += 256) {
        const int node = i / D8, q = i % D8;
        const int n = min(nodeBase + node, N - 1);
        const uint4 u = fbase[(size_t)n * D8 + q];
        *reinterpret_cast<uint4*>(&A_s[node * STR + DIN + q * 8]) = u;
    }
    __syncthreads();

    const int lane = tid & 63;
    const int wave = tid >> 6;
    const int lr = lane & 15;        // A: m (node); B: n (out); D: col (out)
    const int q  = lane >> 4;        // frag k-quad; D row group
    f32x4 acc[4];
#pragma unroll
    for (int t = 0; t < 4; ++t) {
        const float b = bias[t * 16 + lr];
        acc[t] = (f32x4){b, b, b, b};
    }
    const unsigned short* Arow = &A_s[(wave * 16 + lr) * STR + q * 8];
    for (int s = 0; s < nSteps; ++s) {    // runtime: no full unroll
        const bf16x8 af = *reinterpret_cast<const bf16x8*>(Arow + s * 32);
#pragma unroll
        for (int t = 0; t < 4; ++t) {
            const size_t boff = (size_t)(t * 16 + lr) * K + s * 32 + q * 8;
            const bf16x8 bh = *reinterpret_cast<const bf16x8*>(whi + boff);
            const bf16x8 bl = *reinterpret_cast<const bf16x8*>(wlo + boff);
            acc[t] = __builtin_amdgcn_mfma_f32_16x16x32_bf16(af, bh, acc[t], 0, 0, 0);
            acc[t] = __builtin_amdgcn_mfma_f32_16x16x32_bf16(af, bl, acc[t], 0, 0, 0);
        }
    }

    // D layout: row(node local 16) = q*4 + reg, col(out) = t*16 + lr
    if (POOL) {
        float ag[4] = {0.f, 0.f, 0.f, 0.f};
        int gcur = -1;
        for (int reg = 0; reg < 4; ++reg) {
            const int n = nodeBase + wave * 16 + q * 4 + reg;
            if (n >= N) break;
            const int g = batch[n];              // sorted
            if (g != gcur) {
                if (gcur >= 0) {
#pragma unroll
                    for (int t = 0; t < 4; ++t)
                        atomicAdd(&pool_sum[(size_t)gcur * 64 + t * 16 + lr], ag[t]);
                }
                gcur = g;
                ag[0] = ag[1] = ag[2] = ag[3] = 0.f;
            }
#pragma unroll
            for (int t = 0; t < 4; ++t)
                ag[t] += fmaxf(acc[t][reg], 0.0f);
        }
        if (gcur >= 0) {
#pragma unroll
            for (int t = 0; t < 4; ++t)
                atomicAdd(&pool_sum[(size_t)gcur * 64 + t * 16 + lr], ag[t]);
        }
    } else {
        for (int reg = 0; reg < 4; ++reg) {
            const int n = nodeBase + wave * 16 + q * 4 + reg;
            if (n >= N) break;
#pragma unroll
            for (int t = 0; t < 4; ++t)
                houtb[(size_t)n * 64 + t * 16 + lr] = f2bf(fmaxf(acc[t][reg], 0.0f));
        }
    }
}

// ---------- head ----------

__global__ void final_kernel(const float* __restrict__ pool_sum,
                             const int* __restrict__ cnt,
                             const float* __restrict__ W_lin,
                             const float* __restrict__ b_lin,
                             float* __restrict__ out, int G) {
    int t = blockIdx.x * blockDim.x + threadIdx.x;
    if (t >= G * 2) return;
    int g = t >> 1, o = t & 1;
    float inv = 1.0f / fmaxf((float)cnt[g], 1.0f);
    float acc = b_lin[o];
#pragma unroll
    for (int c = 0; c < 64; ++c)
        acc = fmaf(pool_sum[(size_t)g * 64 + c] * inv, W_lin[o * 64 + c], acc);
    out[t] = acc;
}

extern "C" void kernel_launch(void* const* d_in, const int* in_sizes, int n_in,
                              void* d_out, int out_size, void* d_ws, size_t ws_size,
                              hipStream_t stream) {
    const float* x     = (const float*)d_in[0];
    const int*   ei    = (const int*)d_in[1];
    const int*   batch = (const int*)d_in[2];
    const float* W1_l  = (const float*)d_in[3];
    const float* b1    = (const float*)d_in[4];
    const float* W1_r  = (const float*)d_in[5];
    const float* W2_l  = (const float*)d_in[6];
    const float* b2    = (const float*)d_in[7];
    const float* W2_r  = (const float*)d_in[8];
    const float* W_lin = (const float*)d_in[9];
    const float* b_lin = (const float*)d_in[10];

    const int N = in_sizes[0] / 32;
    const int E = in_sizes[1] / 2;
    const int G = out_size / 2;
    const int* src = ei;
    const int* dst = ei + E;
    const int NB = (N + BNODES - 1) >> BSHIFT;   // 196 for N=200000

    char* p = (char*)d_ws;
    auto carve = [&](size_t bytes) -> void* {
        void* r = (void*)p;
        p += (bytes + (WS_ALIGN - 1)) / WS_ALIGN * WS_ALIGN;
        return r;
    };
    int*            bucketCount  = (int*)carve(256 * 4);
    int*            bucketBase   = (int*)carve(257 * 4);
    int*            bucketCursor = (int*)carve(256 * 4);
    unsigned*       bucketData   = (unsigned*)carve((size_t)E * 4);
    int*            offsets      = (int*)carve((size_t)(N + 1) * 4);
    int*            csr_src      = (int*)carve((size_t)E * 4);
    unsigned short* xb           = (unsigned short*)carve((size_t)N * 32 * 2);
    unsigned short* h1b          = (unsigned short*)carve((size_t)N * 64 * 2);
    unsigned short* whi1         = (unsigned short*)carve(64 * 64 * 2);
    unsigned short* wlo1         = (unsigned short*)carve(64 * 64 * 2);
    unsigned short* whi2         = (unsigned short*)carve(64 * 128 * 2);
    unsigned short* wlo2         = (unsigned short*)carve(64 * 128 * 2);
    float*          pool         = (float*)carve((size_t)G * 64 * 4);
    int*            cnt          = (int*)carve((size_t)G * 4);
    float*          out          = (float*)d_out;

    hipMemsetAsync(bucketCount, 0, 256 * 4, stream);
    hipMemsetAsync(pool, 0, (size_t)G * 64 * 4, stream);
    hipMemsetAsync(cnt, 0, (size_t)G * 4, stream);

    const int TB = 256;
    cnt_kernel<<<(N + TB - 1) / TB, TB, 0, stream>>>(batch, cnt, N);
    cvt_kernel<<<((N * 32 / 4) + TB - 1) / TB, TB, 0, stream>>>(x, xb, N * 32 / 4);
    wprep_kernel<<<(64 * 64 + TB - 1) / TB, TB, 0, stream>>>(W1_l, W1_r, whi1, wlo1, 32);
    wprep_kernel<<<(64 * 128 + TB - 1) / TB, TB, 0, stream>>>(W2_l, W2_r, whi2, wlo2, 64);
    bucket_hist_kernel<<<1024, TB, 0, stream>>>(dst, bucketCount, E);
    bucket_scan_kernel<<<1, TB, 0, stream>>>(bucketCount, bucketBase, bucketCursor, NB, E);
    bucket_scatter_kernel<<<(E + EPB - 1) / EPB, TB, 0, stream>>>(src, dst, bucketCursor,
                                                                  bucketData, E, NB);
    csr_build_kernel<<<NB, TB, 0, stream>>>(bucketData, bucketBase, offsets, csr_src, N, E, NB);

    // layer 1: fused gather-mean(xb) + MFMA 32->64 + relu -> h1b (bf16)
    mfma_fused_kernel<32, false><<<(N + 63) / 64, TB, 0, stream>>>(
        xb, csr_src, offsets, whi1, wlo1, b1, h1b, nullptr, nullptr, N, 2);

    // layer 2: fused gather-mean(h1b) + MFMA 64->64 + relu + pool
    mfma_fused_kernel<64, true><<<(N + 63) / 64, TB, 0, stream>>>(
        h1b, csr_src, offsets, whi2, wlo2, b2, nullptr, batch, pool, N, 4);

    final_kernel<<<(G * 2 + TB - 1) / TB, TB, 0, stream>>>(pool, cnt, W_lin, b_lin, out, G);
}

// Round 16
// 432.529 us; speedup vs baseline: 1.0495x; 1.0495x over previous
//
#include <hip/hip_runtime.h>
#include <hip/hip_bf16.h>

// JetGNN: 2-layer SAGEConv(mean) + ReLU + global_mean_pool + Linear(64->2)
// R1: hierarchical scan. R2: bucketed counting-sort CSR build.
// R3: run-flush pool. R4: agg unroll WIN. R5-R8: wave-uniform dense dead end.
// R9: LDS-tiled GEMM WIN. R10: bf16 gather WIN. R11: runtime kIter (VGPR fix).
// R12: MFMA dense WIN. R13: agg bf16-out WIN (gather at byte floor ~3.5TB/s).
// R14: fused gather+MFMA w/ LDS B: block barrier stragglers, 1.77TB/s gather.
// R15: B-from-global in-loop: vmcnt serialization, BOTH phases slower. FAILED.
// R16: barrier-free, LDS-free fusion: lane (lr,q) gather-means exactly its own
//      A-frag channels of node wave*16+lr (A born in registers; self chunks
//      bitcast bf16); B frags (single-bf16) loaded ONCE into 64 VGPRs before
//      the loop -> MFMA loop has zero loads, full unroll safe. Stragglers
//      stall only their wave. Weight lo-residual dropped (absmax ~1e-3 pred).

#define WS_ALIGN 64
#define EPB 4096          // edges per block in bucket_scatter (256 thr x 16)
#define BSHIFT 10         // 1024 nodes per bucket
#define BNODES 1024

typedef short bf16x8 __attribute__((ext_vector_type(8)));
typedef float f32x4 __attribute__((ext_vector_type(4)));

union U16x8 { uint4 u; bf16x8 v; };

__device__ inline unsigned short f2bf(float f) {   // RNE f32->bf16 (finite inputs)
    unsigned u = __float_as_uint(f);
    return (unsigned short)((u + 0x7fffu + ((u >> 16) & 1u)) >> 16);
}

__device__ inline void acc8(const uint4 u, float* a) {  // 8 bf16 -> fp32 accumulate
    a[0] += __uint_as_float(u.x << 16);
    a[1] += __uint_as_float(u.x & 0xffff0000u);
    a[2] += __uint_as_float(u.y << 16);
    a[3] += __uint_as_float(u.y & 0xffff0000u);
    a[4] += __uint_as_float(u.z << 16);
    a[5] += __uint_as_float(u.z & 0xffff0000u);
    a[6] += __uint_as_float(u.w << 16);
    a[7] += __uint_as_float(u.w & 0xffff0000u);
}

// ---------- pooling counts ----------

__global__ void cnt_kernel(const int* __restrict__ batch, int* __restrict__ cnt, int N) {
    int i = blockIdx.x * blockDim.x + threadIdx.x;
    if (i < N) atomicAdd(&cnt[batch[i]], 1);
}

// ---------- x (f32) -> xb (bf16) ----------

__global__ void cvt_kernel(const float* __restrict__ x, unsigned short* __restrict__ xb,
                           int total4) {
    int i = blockIdx.x * blockDim.x + threadIdx.x;
    if (i >= total4) return;
    const float4 v = reinterpret_cast<const float4*>(x)[i];
    ushort4 o;
    o.x = f2bf(v.x); o.y = f2bf(v.y); o.z = f2bf(v.z); o.w = f2bf(v.w);
    reinterpret_cast<ushort4*>(xb)[i] = o;
}

// ---------- weight prepack: [Wl|Wr] rows -> bf16 ----------

__global__ void wprep_kernel(const float* __restrict__ Wl, const float* __restrict__ Wr,
                             unsigned short* __restrict__ whi, int DIN) {
    const int K = 2 * DIN;
    int idx = blockIdx.x * blockDim.x + threadIdx.x;
    if (idx >= 64 * K) return;
    const int o = idx / K, k = idx % K;
    const float v = (k < DIN) ? Wl[o * DIN + k] : Wr[o * DIN + (k - DIN)];
    whi[idx] = f2bf(v);
}

// ---------- bucketed CSR construction ----------

__global__ __launch_bounds__(256) void bucket_hist_kernel(const int* __restrict__ dst,
                                                          int* __restrict__ bucketCount, int E) {
    __shared__ int hist[256];
    const int t = threadIdx.x;
    hist[t] = 0;
    __syncthreads();
    for (int e = blockIdx.x * blockDim.x + t; e < E; e += gridDim.x * blockDim.x)
        atomicAdd(&hist[dst[e] >> BSHIFT], 1);
    __syncthreads();
    if (hist[t] > 0) atomicAdd(&bucketCount[t], hist[t]);
}

__global__ __launch_bounds__(256) void bucket_scan_kernel(const int* __restrict__ bucketCount,
                                                          int* __restrict__ bucketBase,
                                                          int* __restrict__ bucketCursor,
                                                          int NB, int E) {
    __shared__ int s[256];
    const int t = threadIdx.x;
    int v = (t < NB) ? bucketCount[t] : 0;
    s[t] = v;
    __syncthreads();
    for (int off = 1; off < 256; off <<= 1) {
        int u = (t >= off) ? s[t - off] : 0;
        __syncthreads();
        s[t] += u;
        __syncthreads();
    }
    int excl = s[t] - v;
    if (t < NB) { bucketBase[t] = excl; bucketCursor[t] = excl; }
    if (t == 0) bucketBase[NB] = E;
}

__global__ __launch_bounds__(256) void bucket_scatter_kernel(const int* __restrict__ src,
                                                             const int* __restrict__ dst,
                                                             int* __restrict__ bucketCursor,
                                                             unsigned* __restrict__ bucketData,
                                                             int E, int NB) {
    __shared__ int hist[256];
    __shared__ int cur[256];
    const int t = threadIdx.x;
    hist[t] = 0;
    __syncthreads();
    const int eBase = blockIdx.x * EPB + t;
    int s[16], b[16], dl[16];
#pragma unroll
    for (int j = 0; j < 16; ++j) {
        int e = eBase + j * 256;
        if (e < E) {
            int d = dst[e];
            s[j]  = src[e];
            b[j]  = d >> BSHIFT;
            dl[j] = d & (BNODES - 1);
            atomicAdd(&hist[b[j]], 1);
        } else {
            b[j] = -1;
        }
    }
    __syncthreads();
    if (t < NB && hist[t] > 0) cur[t] = atomicAdd(&bucketCursor[t], hist[t]);
    __syncthreads();
#pragma unroll
    for (int j = 0; j < 16; ++j) {
        if (b[j] >= 0) {
            int pos = atomicAdd(&cur[b[j]], 1);
            bucketData[pos] = ((unsigned)s[j] << BSHIFT) | (unsigned)dl[j];
        }
    }
}

__global__ __launch_bounds__(256) void csr_build_kernel(const unsigned* __restrict__ bucketData,
                                                        const int* __restrict__ bucketBase,
                                                        int* __restrict__ offsets,
                                                        int* __restrict__ csr_src,
                                                        int N, int E, int NB) {
    __shared__ int cnt[BNODES];
    __shared__ int sscan[256];
    __shared__ int cur[BNODES];
    const int t   = threadIdx.x;
    const int bkt = blockIdx.x;
    const int beg = bucketBase[bkt];
    const int end = bucketBase[bkt + 1];
    for (int i = t; i < BNODES; i += 256) cnt[i] = 0;
    __syncthreads();
    for (int k = beg + t; k < end; k += 256)
        atomicAdd(&cnt[bucketData[k] & (BNODES - 1)], 1);
    __syncthreads();
    int local[4];
    int sum = 0;
#pragma unroll
    for (int j = 0; j < 4; ++j) { local[j] = sum; sum += cnt[t * 4 + j]; }
    sscan[t] = sum;
    __syncthreads();
    for (int off = 1; off < 256; off <<= 1) {
        int v = (t >= off) ? sscan[t - off] : 0;
        __syncthreads();
        sscan[t] += v;
        __syncthreads();
    }
    int base = (t > 0) ? sscan[t - 1] : 0;
#pragma unroll
    for (int j = 0; j < 4; ++j) cur[t * 4 + j] = base + local[j];
    __syncthreads();
    for (int i = t; i < BNODES; i += 256) {
        int node = (bkt << BSHIFT) + i;
        if (node <= N) offsets[node] = beg + cur[i];
    }
    if (bkt == NB - 1 && t == 0 && (NB << BSHIFT) == N) offsets[N] = E;
    __syncthreads();
    for (int k = beg + t; k < end; k += 256) {
        unsigned v = bucketData[k];
        int d   = (int)(v & (BNODES - 1));
        int pos = beg + atomicAdd(&cur[d], 1);
        csr_src[pos] = (int)(v >> BSHIFT);
    }
}

// ---------- barrier-free LDS-free fused gather + MFMA ----------
// Block = 64 nodes (4 waves x 16), 64 outs. Lane (lr=lane&15, q=lane>>4) of
// wave w gather-means node w*16+lr over channel chunks {m*32+q*8..+8} — which
// are EXACTLY its A-frag channels -> A built in registers. Self chunks are
// bf16 bitcasts. B frags (bf16) loaded once from prepacked whi (L2-hot).
// MFMA loop has no loads -> full unroll safe. No __syncthreads anywhere.
// Layouts per m89/m91: A[m=lane&15][k=q*8+j], B[k][n], D col=lr,row=q*4+reg.

template <int DIN, bool POOL>
__launch_bounds__(256)
__global__ void mfma_fused_kernel(const unsigned short* __restrict__ featb,
                                  const int* __restrict__ csr_src,
                                  const int* __restrict__ offsets,
                                  const unsigned short* __restrict__ whi,
                                  const float* __restrict__ bias,
                                  unsigned short* __restrict__ houtb,
                                  const int* __restrict__ batch,
                                  float* __restrict__ pool_sum,
                                  int N) {
    constexpr int K  = 2 * DIN;       // 64 / 128
    constexpr int NS = K / 32;        // MFMA k-steps: 2 / 4
    constexpr int MC = NS / 2;        // mean chunks per lane: 1 / 2
    constexpr int D8 = DIN / 8;       // uint4 per feature row: 4 / 8
    const int tid  = threadIdx.x;
    const int wave = tid >> 6;
    const int lane = tid & 63;
    const int lr   = lane & 15;
    const int q    = lane >> 4;
    const int nodeBase = blockIdx.x * 64;
    const int myNode = min(nodeBase + wave * 16 + lr, N - 1);
    const uint4* fbase = reinterpret_cast<const uint4*>(featb);

    // B frags: rows t*16+lr, k = s*32 + q*8 .. +8 (one-time, L2-hot)
    bf16x8 bh[4][NS];
#pragma unroll
    for (int t = 0; t < 4; ++t)
#pragma unroll
        for (int s = 0; s < NS; ++s)
            bh[t][s] = *reinterpret_cast<const bf16x8*>(
                whi + (size_t)(t * 16 + lr) * K + s * 32 + q * 8);

    // gather-mean of this lane's chunks (m*4+q) of myNode's neighbors
    float am[MC * 8];
#pragma unroll
    for (int i = 0; i < MC * 8; ++i) am[i] = 0.f;
    const int beg = offsets[myNode];
    const int end = offsets[myNode + 1];
    int k = beg;
    for (; k + 4 <= end; k += 4) {
        int sidx[4];
#pragma unroll
        for (int j = 0; j < 4; ++j) sidx[j] = csr_src[k + j];
        uint4 u[4][MC];
#pragma unroll
        for (int j = 0; j < 4; ++j)
#pragma unroll
            for (int m = 0; m < MC; ++m)
                u[j][m] = fbase[(size_t)sidx[j] * D8 + m * 4 + q];
#pragma unroll
        for (int j = 0; j < 4; ++j)
#pragma unroll
            for (int m = 0; m < MC; ++m)
                acc8(u[j][m], am + m * 8);
    }
    for (; k < end; ++k) {
        const int s0 = csr_src[k];
#pragma unroll
        for (int m = 0; m < MC; ++m)
            acc8(fbase[(size_t)s0 * D8 + m * 4 + q], am + m * 8);
    }
    const float inv = 1.0f / fmaxf((float)(end - beg), 1.0f);
    bf16x8 afm[MC], afs[MC];
#pragma unroll
    for (int m = 0; m < MC; ++m) {
#pragma unroll
        for (int j = 0; j < 8; ++j)
            afm[m][j] = (short)f2bf(am[m * 8 + j] * inv);
        U16x8 t16;
        t16.u = fbase[(size_t)myNode * D8 + m * 4 + q];   // self row chunk (bf16)
        afs[m] = t16.v;
    }

    // MFMA: no loads inside; full unroll safe
    f32x4 acc[4];
#pragma unroll
    for (int t = 0; t < 4; ++t) {
        const float b = bias[t * 16 + lr];
        acc[t] = (f32x4){b, b, b, b};
    }
#pragma unroll
    for (int s = 0; s < NS; ++s) {
        const bf16x8 af = (s < MC) ? afm[s] : afs[s - MC];
#pragma unroll
        for (int t = 0; t < 4; ++t)
            acc[t] = __builtin_amdgcn_mfma_f32_16x16x32_bf16(af, bh[t][s], acc[t], 0, 0, 0);
    }

    // D layout: row(node local 16) = q*4 + reg, col(out) = t*16 + lr
    if (POOL) {
        float ag[4] = {0.f, 0.f, 0.f, 0.f};
        int gcur = -1;
        for (int reg = 0; reg < 4; ++reg) {
            const int n = nodeBase + wave * 16 + q * 4 + reg;
            if (n >= N) break;
            const int g = batch[n];              // sorted
            if (g != gcur) {
                if (gcur >= 0) {
#pragma unroll
                    for (int t = 0; t < 4; ++t)
                        atomicAdd(&pool_sum[(size_t)gcur * 64 + t * 16 + lr], ag[t]);
                }
                gcur = g;
                ag[0] = ag[1] = ag[2] = ag[3] = 0.f;
            }
#pragma unroll
            for (int t = 0; t < 4; ++t)
                ag[t] += fmaxf(acc[t][reg], 0.0f);
        }
        if (gcur >= 0) {
#pragma unroll
            for (int t = 0; t < 4; ++t)
                atomicAdd(&pool_sum[(size_t)gcur * 64 + t * 16 + lr], ag[t]);
        }
    } else {
        for (int reg = 0; reg < 4; ++reg) {
            const int n = nodeBase + wave * 16 + q * 4 + reg;
            if (n >= N) break;
#pragma unroll
            for (int t = 0; t < 4; ++t)
                houtb[(size_t)n * 64 + t * 16 + lr] = f2bf(fmaxf(acc[t][reg], 0.0f));
        }
    }
}

// ---------- head ----------

__global__ void final_kernel(const float* __restrict__ pool_sum,
                             const int* __restrict__ cnt,
                             const float* __restrict__ W_lin,
                             const float* __restrict__ b_lin,
                             float* __restrict__ out, int G) {
    int t = blockIdx.x * blockDim.x + threadIdx.x;
    if (t >= G * 2) return;
    int g = t >> 1, o = t & 1;
    float inv = 1.0f / fmaxf((float)cnt[g], 1.0f);
    float acc = b_lin[o];
#pragma unroll
    for (int c = 0; c < 64; ++c)
        acc = fmaf(pool_sum[(size_t)g * 64 + c] * inv, W_lin[o * 64 + c], acc);
    out[t] = acc;
}

extern "C" void kernel_launch(void* const* d_in, const int* in_sizes, int n_in,
                              void* d_out, int out_size, void* d_ws, size_t ws_size,
                              hipStream_t stream) {
    const float* x     = (const float*)d_in[0];
    const int*   ei    = (const int*)d_in[1];
    const int*   batch = (const int*)d_in[2];
    const float* W1_l  = (const float*)d_in[3];
    const float* b1    = (const float*)d_in[4];
    const float* W1_r  = (const float*)d_in[5];
    const float* W2_l  = (const float*)d_in[6];
    const float* b2    = (const float*)d_in[7];
    const float* W2_r  = (const float*)d_in[8];
    const float* W_lin = (const float*)d_in[9];
    const float* b_lin = (const float*)d_in[10];

    const int N = in_sizes[0] / 32;
    const int E = in_sizes[1] / 2;
    const int G = out_size / 2;
    const int* src = ei;
    const int* dst = ei + E;
    const int NB = (N + BNODES - 1) >> BSHIFT;   // 196 for N=200000

    char* p = (char*)d_ws;
    auto carve = [&](size_t bytes) -> void* {
        void* r = (void*)p;
        p += (bytes + (WS_ALIGN - 1)) / WS_ALIGN * WS_ALIGN;
        return r;
    };
    int*            bucketCount  = (int*)carve(256 * 4);
    int*            bucketBase   = (int*)carve(257 * 4);
    int*            bucketCursor = (int*)carve(256 * 4);
    unsigned*       bucketData   = (unsigned*)carve((size_t)E * 4);
    int*            offsets      = (int*)carve((size_t)(N + 1) * 4);
    int*            csr_src      = (int*)carve((size_t)E * 4);
    unsigned short* xb           = (unsigned short*)carve((size_t)N * 32 * 2);
    unsigned short* h1b          = (unsigned short*)carve((size_t)N * 64 * 2);
    unsigned short* whi1         = (unsigned short*)carve(64 * 64 * 2);
    unsigned short* whi2         = (unsigned short*)carve(64 * 128 * 2);
    float*          pool         = (float*)carve((size_t)G * 64 * 4);
    int*            cnt          = (int*)carve((size_t)G * 4);
    float*          out          = (float*)d_out;

    hipMemsetAsync(bucketCount, 0, 256 * 4, stream);
    hipMemsetAsync(pool, 0, (size_t)G * 64 * 4, stream);
    hipMemsetAsync(cnt, 0, (size_t)G * 4, stream);

    const int TB = 256;
    cnt_kernel<<<(N + TB - 1) / TB, TB, 0, stream>>>(batch, cnt, N);
    cvt_kernel<<<((N * 32 / 4) + TB - 1) / TB, TB, 0, stream>>>(x, xb, N * 32 / 4);
    wprep_kernel<<<(64 * 64 + TB - 1) / TB, TB, 0, stream>>>(W1_l, W1_r, whi1, 32);
    wprep_kernel<<<(64 * 128 + TB - 1) / TB, TB, 0, stream>>>(W2_l, W2_r, whi2, 64);
    bucket_hist_kernel<<<1024, TB, 0, stream>>>(dst, bucketCount, E);
    bucket_scan_kernel<<<1, TB, 0, stream>>>(bucketCount, bucketBase, bucketCursor, NB, E);
    bucket_scatter_kernel<<<(E + EPB - 1) / EPB, TB, 0, stream>>>(src, dst, bucketCursor,
                                                                  bucketData, E, NB);
    csr_build_kernel<<<NB, TB, 0, stream>>>(bucketData, bucketBase, offsets, csr_src, N, E, NB);

    // layer 1: fused gather-mean(xb) + MFMA 32->64 + relu -> h1b (bf16)
    mfma_fused_kernel<32, false><<<(N + 63) / 64, TB, 0, stream>>>(
        xb, csr_src, offsets, whi1, b1, h1b, nullptr, nullptr, N);

    // layer 2: fused gather-mean(h1b) + MFMA 64->64 + relu + pool
    mfma_fused_kernel<64, true><<<(N + 63) / 64, TB, 0, stream>>>(
        h1b, csr_src, offsets, whi2, b2, nullptr, batch, pool, N);

    final_kernel<<<(G * 2 + TB - 1) / TB, TB, 0, stream>>>(pool, cnt, W_lin, b_lin, out, G);
}